// Round 1
// baseline (489.154 us; speedup 1.0000x reference)
//
#include <hip/hip_runtime.h>
#include <math.h>

// PlainVoxels volume renderer, MI355X.
// R=2048 rays x S=240 samples; 8-corner trilinear hash-grid lookup (table:
// 20.48M x 5 f32 = 102 MB, L3-resident) + analytic gradient + online
// transmittance (per-ray prefix scan).
//
// Decomposition: 1 ray per 256-thread block; thread s = sample s (240 active).
// cumsum(tau): wave __shfl_up scan + cross-wave LDS offsets.
// 8-channel output reduce: __shfl_xor wave reduce + LDS partials.
//
// FP discipline: contract(off) + true division so floor(p/CELL) matches XLA
// bit-for-bit (gradient is discontinuous across cell boundaries, so a flipped
// cell changes a normal by O(1)).

namespace {
constexpr int   R_    = 2048;
constexpr int   S_    = 240;
constexpr float DT_   = 0.01f;
constexpr float CELL_ = 0.015f;
constexpr float MINB_ = 0.015f;
constexpr int   TSZ_  = 40000 * 512;   // 20,480,000
constexpr float EPS_  = 1e-12f;
}

__global__ __launch_bounds__(256)
void pv_render(const float* __restrict__ rays_o,
               const float* __restrict__ rays_d,
               const float* __restrict__ rays_d_norm,
               const float* __restrict__ nearv,
               const float* __restrict__ farv,
               const float* __restrict__ table,
               const float* __restrict__ betav,
               float* __restrict__ out)
{
#pragma clang fp contract(off)
    const int r    = blockIdx.x;
    const int tid  = threadIdx.x;
    const int lane = tid & 63;
    const int wid  = tid >> 6;

    __shared__ float s_wsum[4];
    __shared__ float s_red[4][8];

    const float nr = nearv[r];
    const float fr = farv[r];
    const float ox = rays_o[3*r+0], oy = rays_o[3*r+1], oz = rays_o[3*r+2];
    const float dx = rays_d[3*r+0], dy = rays_d[3*r+1], dz = rays_d[3*r+2];
    const float b  = MINB_ + fabsf(betav[0]);

    // sample interval (threads >= S_ compute harmless values, masked below)
    const float t0 = nr + (float)tid * DT_;
    const float t1 = t0 + DT_;
    const float tm = 0.5f * (t0 + t1);
    const bool  sample_ok = (tid < S_);
    const bool  valid     = sample_ok && (t1 <= fr);

    float emb0 = 0.f, emb1 = 0.f, emb2 = 0.f, emb3 = 0.f;
    float ggx = 0.f, ggy = 0.f, ggz = 0.f;

    if (sample_ok) {
        const float px = ox + tm * dx;
        const float py = oy + tm * dy;
        const float pz = oz + tm * dz;
        // true division: matches XLA's divide HLO (floor() cell assignment
        // must agree bit-for-bit — gradient is discontinuous across cells)
        const float ux = px / CELL_;
        const float uy = py / CELL_;
        const float uz = pz / CELL_;
        const float x0 = floorf(ux), y0 = floorf(uy), z0 = floorf(uz);
        const float fx = ux - x0, fy = uy - y0, fz = uz - z0;
        const int ix = (int)x0, iy = (int)y0, iz = (int)z0;

        const float wxa[2] = {1.f - fx, fx};
        const float wya[2] = {1.f - fy, fy};
        const float wza[2] = {1.f - fz, fz};

        // int32-wrap hash components (unsigned mul == XLA int32 overflow wrap)
        const unsigned hxs[2] = {(unsigned)ix * 73856093u,
                                 (unsigned)(ix + 1) * 73856093u};
        const unsigned hys[2] = {(unsigned)iy * 19349663u,
                                 (unsigned)(iy + 1) * 19349663u};
        const unsigned hzs[2] = {(unsigned)iz * 83492791u,
                                 (unsigned)(iz + 1) * 83492791u};

#pragma unroll
        for (int i = 0; i < 2; ++i) {
#pragma unroll
            for (int j = 0; j < 2; ++j) {
#pragma unroll
                for (int k = 0; k < 2; ++k) {
                    const int vh = (int)(hxs[i] ^ hys[j] ^ hzs[k]);
                    int h = vh % TSZ_;           // trunc-mod
                    if (h < 0) h += TSZ_;        // -> floor-mod (Python/JAX)
                    const float* row = table + (size_t)h * 5u;
                    const float v0 = row[0];
                    const float v1 = row[1];
                    const float v2 = row[2];
                    const float v3 = row[3];
                    const float wyz = wya[j] * wza[k];
                    const float wxz = wxa[i] * wza[k];
                    const float wxy = wxa[i] * wya[j];
                    const float w   = wxa[i] * wyz;
                    emb0 += w * v0;
                    emb1 += w * v1;
                    emb2 += w * v2;
                    emb3 += w * v3;
                    // d w / d f: sign per axis, times the other two weights
                    ggx += (i ? 1.f : -1.f) * wyz * v0;
                    ggy += (j ? 1.f : -1.f) * wxz * v0;
                    ggz += (k ? 1.f : -1.f) * wxy * v0;
                }
            }
        }
        // chain rule through u = p / CELL (JAX div-rule divides the cotangent)
        ggx = ggx / CELL_;
        ggy = ggy / CELL_;
        ggz = ggz / CELL_;
    }

    // normals
    const float gl = sqrtf(ggx * ggx + ggy * ggy + ggz * ggz);
    const float gd = fmaxf(gl, EPS_);
    const float nx = ggx / gd, ny = ggy / gd, nz = ggz / gd;

    // Laplace-CDF density
    const float sdf = emb0;
    const float sg  = (sdf > 0.f) ? 1.f : ((sdf < 0.f) ? -1.f : 0.f);
    float sigma = (0.5f + 0.5f * sg * expm1f(-fabsf(sdf) / b)) * (1.0f / b);
    sigma = valid ? sigma : 0.f;
    const float tau = sigma * DT_;

    // inclusive scan of tau: wave shfl_up scan + cross-wave offsets
    float incl = tau;
#pragma unroll
    for (int off = 1; off < 64; off <<= 1) {
        const float t = __shfl_up(incl, off, 64);
        if (lane >= off) incl += t;
    }
    if (lane == 63) s_wsum[wid] = incl;
    __syncthreads();
    float woff = 0.f;
    for (int i = 0; i < wid; ++i) woff += s_wsum[i];
    incl += woff;

    const float trans = expf(-(incl - tau));
    const float alpha = -expm1f(-tau);
    const float wgt   = valid ? trans * alpha : 0.f;

    // 8-channel weighted reduce: rgb(3), w*tm, nrm(3), acc
    float a0 = wgt * emb1;
    float a1 = wgt * emb2;
    float a2 = wgt * emb3;
    float a3 = wgt * tm;
    float a4 = wgt * nx;
    float a5 = wgt * ny;
    float a6 = wgt * nz;
    float a7 = wgt;

#pragma unroll
    for (int m = 1; m < 64; m <<= 1) {
        a0 += __shfl_xor(a0, m, 64);
        a1 += __shfl_xor(a1, m, 64);
        a2 += __shfl_xor(a2, m, 64);
        a3 += __shfl_xor(a3, m, 64);
        a4 += __shfl_xor(a4, m, 64);
        a5 += __shfl_xor(a5, m, 64);
        a6 += __shfl_xor(a6, m, 64);
        a7 += __shfl_xor(a7, m, 64);
    }
    if (lane == 0) {
        s_red[wid][0] = a0; s_red[wid][1] = a1;
        s_red[wid][2] = a2; s_red[wid][3] = a3;
        s_red[wid][4] = a4; s_red[wid][5] = a5;
        s_red[wid][6] = a6; s_red[wid][7] = a7;
    }
    __syncthreads();
    if (tid < 8) {
        float acc = s_red[0][tid] + s_red[1][tid] + s_red[2][tid] + s_red[3][tid];
        if (tid == 3) acc /= rays_d_norm[r];   // depth channel
        out[r * 8 + tid] = acc;
    }
}

extern "C" void kernel_launch(void* const* d_in, const int* in_sizes, int n_in,
                              void* d_out, int out_size, void* d_ws, size_t ws_size,
                              hipStream_t stream) {
    const float* rays_o      = (const float*)d_in[0];
    const float* rays_d      = (const float*)d_in[1];
    const float* rays_d_norm = (const float*)d_in[2];
    const float* nearv       = (const float*)d_in[3];
    const float* farv        = (const float*)d_in[4];
    const float* table       = (const float*)d_in[5];
    const float* betav       = (const float*)d_in[6];
    float* out = (float*)d_out;

    pv_render<<<dim3(R_), dim3(256), 0, stream>>>(
        rays_o, rays_d, rays_d_norm, nearv, farv, table, betav, out);
}

// Round 2
// 481.591 us; speedup vs baseline: 1.0157x; 1.0157x over previous
//
#include <hip/hip_runtime.h>
#include <math.h>

// PlainVoxels volume renderer, MI355X — R1.
// R=2048 rays x S=240 samples; 8-corner trilinear hash-grid lookup (table:
// 20.48M x 5 f32 = 410 MB, > L3) + analytic gradient + online transmittance.
//
// R1 changes vs R0 (theory: bound on L2 request throughput of divergent
// gathers, not bytes):
//  * each 16B row read issued as ONE __builtin_memcpy -> float4 (compiler
//    emits global_load_dwordx4 if gfx950 unaligned access allows; else falls
//    back to 4x dword = R0 behavior). 32 -> 8 VMEM instrs/thread.
//  * gathers skipped entirely for invalid samples (t1 > far): reference
//    masks their contribution with w=0, so lookups are dead. ~25% fewer
//    gathers on average.
//
// FP discipline: contract(off) + true division so floor(p/CELL) matches XLA
// bit-for-bit (trilinear gradient is discontinuous across cell boundaries).

namespace {
constexpr int   R_    = 2048;
constexpr int   S_    = 240;
constexpr float DT_   = 0.01f;
constexpr float CELL_ = 0.015f;
constexpr float MINB_ = 0.015f;
constexpr int   TSZ_  = 40000 * 512;   // 20,480,000
constexpr float EPS_  = 1e-12f;
}

__global__ __launch_bounds__(256)
void pv_render(const float* __restrict__ rays_o,
               const float* __restrict__ rays_d,
               const float* __restrict__ rays_d_norm,
               const float* __restrict__ nearv,
               const float* __restrict__ farv,
               const float* __restrict__ table,
               const float* __restrict__ betav,
               float* __restrict__ out)
{
#pragma clang fp contract(off)
    const int r    = blockIdx.x;
    const int tid  = threadIdx.x;
    const int lane = tid & 63;
    const int wid  = tid >> 6;

    __shared__ float s_wsum[4];
    __shared__ float s_red[4][8];

    const float nr = nearv[r];
    const float fr = farv[r];
    const float ox = rays_o[3*r+0], oy = rays_o[3*r+1], oz = rays_o[3*r+2];
    const float dx = rays_d[3*r+0], dy = rays_d[3*r+1], dz = rays_d[3*r+2];
    const float b  = MINB_ + fabsf(betav[0]);

    const float t0 = nr + (float)tid * DT_;
    const float t1 = t0 + DT_;
    const float tm = 0.5f * (t0 + t1);
    const bool  valid = (tid < S_) && (t1 <= fr);

    float emb0 = 0.f, emb1 = 0.f, emb2 = 0.f, emb3 = 0.f;
    float ggx = 0.f, ggy = 0.f, ggz = 0.f;

    if (valid) {   // invalid samples' lookups are dead (w=0 masks them)
        const float px = ox + tm * dx;
        const float py = oy + tm * dy;
        const float pz = oz + tm * dz;
        // true division: floor(p/CELL) must match XLA bit-for-bit
        const float ux = px / CELL_;
        const float uy = py / CELL_;
        const float uz = pz / CELL_;
        const float x0 = floorf(ux), y0 = floorf(uy), z0 = floorf(uz);
        const float fx = ux - x0, fy = uy - y0, fz = uz - z0;
        const int ix = (int)x0, iy = (int)y0, iz = (int)z0;

        const float wxa[2] = {1.f - fx, fx};
        const float wya[2] = {1.f - fy, fy};
        const float wza[2] = {1.f - fz, fz};

        // int32-wrap hash components (unsigned mul == XLA int32 overflow wrap)
        const unsigned hxs[2] = {(unsigned)ix * 73856093u,
                                 (unsigned)(ix + 1) * 73856093u};
        const unsigned hys[2] = {(unsigned)iy * 19349663u,
                                 (unsigned)(iy + 1) * 19349663u};
        const unsigned hzs[2] = {(unsigned)iz * 83492791u,
                                 (unsigned)(iz + 1) * 83492791u};

        // issue all 8 row loads back-to-back (max MLP), one 16B op each
        float4 rv[8];
#pragma unroll
        for (int c = 0; c < 8; ++c) {
            const int i = (c >> 2) & 1, j = (c >> 1) & 1, k = c & 1;
            const int vh = (int)(hxs[i] ^ hys[j] ^ hzs[k]);
            int h = vh % TSZ_;            // trunc-mod
            if (h < 0) h += TSZ_;         // -> floor-mod (Python/JAX)
            __builtin_memcpy(&rv[c], table + (size_t)h * 5u, 16);
        }

#pragma unroll
        for (int c = 0; c < 8; ++c) {
            const int i = (c >> 2) & 1, j = (c >> 1) & 1, k = c & 1;
            const float wyz = wya[j] * wza[k];
            const float wxz = wxa[i] * wza[k];
            const float wxy = wxa[i] * wya[j];
            const float w   = wxa[i] * wyz;
            emb0 += w * rv[c].x;
            emb1 += w * rv[c].y;
            emb2 += w * rv[c].z;
            emb3 += w * rv[c].w;
            ggx += (i ? 1.f : -1.f) * wyz * rv[c].x;
            ggy += (j ? 1.f : -1.f) * wxz * rv[c].x;
            ggz += (k ? 1.f : -1.f) * wxy * rv[c].x;
        }
        // chain rule through u = p / CELL
        ggx = ggx / CELL_;
        ggy = ggy / CELL_;
        ggz = ggz / CELL_;
    }

    // normals (invalid lanes: 0/EPS = 0, masked by wgt=0 anyway)
    const float gl = sqrtf(ggx * ggx + ggy * ggy + ggz * ggz);
    const float gd = fmaxf(gl, EPS_);
    const float nx = ggx / gd, ny = ggy / gd, nz = ggz / gd;

    // Laplace-CDF density
    const float sdf = emb0;
    const float sg  = (sdf > 0.f) ? 1.f : ((sdf < 0.f) ? -1.f : 0.f);
    float sigma = (0.5f + 0.5f * sg * expm1f(-fabsf(sdf) / b)) * (1.0f / b);
    sigma = valid ? sigma : 0.f;
    const float tau = sigma * DT_;

    // inclusive scan of tau: wave shfl_up scan + cross-wave offsets
    float incl = tau;
#pragma unroll
    for (int off = 1; off < 64; off <<= 1) {
        const float t = __shfl_up(incl, off, 64);
        if (lane >= off) incl += t;
    }
    if (lane == 63) s_wsum[wid] = incl;
    __syncthreads();
    float woff = 0.f;
    for (int i = 0; i < wid; ++i) woff += s_wsum[i];
    incl += woff;

    const float trans = expf(-(incl - tau));
    const float alpha = -expm1f(-tau);
    const float wgt   = valid ? trans * alpha : 0.f;

    // 8-channel weighted reduce: rgb(3), w*tm, nrm(3), acc
    float a0 = wgt * emb1;
    float a1 = wgt * emb2;
    float a2 = wgt * emb3;
    float a3 = wgt * tm;
    float a4 = wgt * nx;
    float a5 = wgt * ny;
    float a6 = wgt * nz;
    float a7 = wgt;

#pragma unroll
    for (int m = 1; m < 64; m <<= 1) {
        a0 += __shfl_xor(a0, m, 64);
        a1 += __shfl_xor(a1, m, 64);
        a2 += __shfl_xor(a2, m, 64);
        a3 += __shfl_xor(a3, m, 64);
        a4 += __shfl_xor(a4, m, 64);
        a5 += __shfl_xor(a5, m, 64);
        a6 += __shfl_xor(a6, m, 64);
        a7 += __shfl_xor(a7, m, 64);
    }
    if (lane == 0) {
        s_red[wid][0] = a0; s_red[wid][1] = a1;
        s_red[wid][2] = a2; s_red[wid][3] = a3;
        s_red[wid][4] = a4; s_red[wid][5] = a5;
        s_red[wid][6] = a6; s_red[wid][7] = a7;
    }
    __syncthreads();
    if (tid < 8) {
        float acc = s_red[0][tid] + s_red[1][tid] + s_red[2][tid] + s_red[3][tid];
        if (tid == 3) acc /= rays_d_norm[r];   // depth channel
        out[r * 8 + tid] = acc;
    }
}

extern "C" void kernel_launch(void* const* d_in, const int* in_sizes, int n_in,
                              void* d_out, int out_size, void* d_ws, size_t ws_size,
                              hipStream_t stream) {
    const float* rays_o      = (const float*)d_in[0];
    const float* rays_d      = (const float*)d_in[1];
    const float* rays_d_norm = (const float*)d_in[2];
    const float* nearv       = (const float*)d_in[3];
    const float* farv        = (const float*)d_in[4];
    const float* table       = (const float*)d_in[5];
    const float* betav       = (const float*)d_in[6];
    float* out = (float*)d_out;

    pv_render<<<dim3(R_), dim3(256), 0, stream>>>(
        rays_o, rays_d, rays_d_norm, nearv, farv, table, betav, out);
}

// Round 3
// 481.089 us; speedup vs baseline: 1.0168x; 1.0010x over previous
//
#include <hip/hip_runtime.h>
#include <math.h>

// PlainVoxels volume renderer, MI355X — R2.
// R=2048 rays x S=240 samples; 8-corner trilinear hash-grid lookup (table:
// 20.48M x 5 f32 = 410 MB, > L3) + analytic gradient + online transmittance.
//
// R2 change: force ONE global_load_dwordx4 per 20B table row by casting to
// float4* (asserts 16B alignment; rows are 4B-aligned — CDNA unaligned global
// access handles this, verified by the correctness gate). R1's memcpy was
// split back into 4x dword by LLVM because alignment was provably only 4.
// Theory: gather phase is TA address-processing / request-throughput bound;
// 4x fewer VMEM instructions cuts it ~4x.
//
// FP discipline: contract(off) + true division so floor(p/CELL) matches XLA
// bit-for-bit (trilinear gradient is discontinuous across cell boundaries).

namespace {
constexpr int   R_    = 2048;
constexpr int   S_    = 240;
constexpr float DT_   = 0.01f;
constexpr float CELL_ = 0.015f;
constexpr float MINB_ = 0.015f;
constexpr int   TSZ_  = 40000 * 512;   // 20,480,000
constexpr float EPS_  = 1e-12f;
}

__global__ __launch_bounds__(256)
void pv_render(const float* __restrict__ rays_o,
               const float* __restrict__ rays_d,
               const float* __restrict__ rays_d_norm,
               const float* __restrict__ nearv,
               const float* __restrict__ farv,
               const float* __restrict__ table,
               const float* __restrict__ betav,
               float* __restrict__ out)
{
#pragma clang fp contract(off)
    const int r    = blockIdx.x;
    const int tid  = threadIdx.x;
    const int lane = tid & 63;
    const int wid  = tid >> 6;

    __shared__ float s_wsum[4];
    __shared__ float s_red[4][8];

    const float nr = nearv[r];
    const float fr = farv[r];
    const float ox = rays_o[3*r+0], oy = rays_o[3*r+1], oz = rays_o[3*r+2];
    const float dx = rays_d[3*r+0], dy = rays_d[3*r+1], dz = rays_d[3*r+2];
    const float b  = MINB_ + fabsf(betav[0]);

    const float t0 = nr + (float)tid * DT_;
    const float t1 = t0 + DT_;
    const float tm = 0.5f * (t0 + t1);
    const bool  valid = (tid < S_) && (t1 <= fr);

    float emb0 = 0.f, emb1 = 0.f, emb2 = 0.f, emb3 = 0.f;
    float ggx = 0.f, ggy = 0.f, ggz = 0.f;

    if (valid) {   // invalid samples' lookups are dead (w=0 masks them)
        const float px = ox + tm * dx;
        const float py = oy + tm * dy;
        const float pz = oz + tm * dz;
        // true division: floor(p/CELL) must match XLA bit-for-bit
        const float ux = px / CELL_;
        const float uy = py / CELL_;
        const float uz = pz / CELL_;
        const float x0 = floorf(ux), y0 = floorf(uy), z0 = floorf(uz);
        const float fx = ux - x0, fy = uy - y0, fz = uz - z0;
        const int ix = (int)x0, iy = (int)y0, iz = (int)z0;

        const float wxa[2] = {1.f - fx, fx};
        const float wya[2] = {1.f - fy, fy};
        const float wza[2] = {1.f - fz, fz};

        // int32-wrap hash components (unsigned mul == XLA int32 overflow wrap)
        const unsigned hxs[2] = {(unsigned)ix * 73856093u,
                                 (unsigned)(ix + 1) * 73856093u};
        const unsigned hys[2] = {(unsigned)iy * 19349663u,
                                 (unsigned)(iy + 1) * 19349663u};
        const unsigned hzs[2] = {(unsigned)iz * 83492791u,
                                 (unsigned)(iz + 1) * 83492791u};

        // one 16B global_load_dwordx4 per row (rows are 4B-aligned; CDNA
        // unaligned global access is fine — row h=TSZ-1 reads bytes
        // [409599980,409599996) which is still inside the 409600000B table)
        float4 rv[8];
#pragma unroll
        for (int c = 0; c < 8; ++c) {
            const int i = (c >> 2) & 1, j = (c >> 1) & 1, k = c & 1;
            const int vh = (int)(hxs[i] ^ hys[j] ^ hzs[k]);
            int h = vh % TSZ_;            // trunc-mod
            if (h < 0) h += TSZ_;         // -> floor-mod (Python/JAX)
            rv[c] = *reinterpret_cast<const float4*>(table + (size_t)h * 5u);
        }

#pragma unroll
        for (int c = 0; c < 8; ++c) {
            const int i = (c >> 2) & 1, j = (c >> 1) & 1, k = c & 1;
            const float wyz = wya[j] * wza[k];
            const float wxz = wxa[i] * wza[k];
            const float wxy = wxa[i] * wya[j];
            const float w   = wxa[i] * wyz;
            emb0 += w * rv[c].x;
            emb1 += w * rv[c].y;
            emb2 += w * rv[c].z;
            emb3 += w * rv[c].w;
            ggx += (i ? 1.f : -1.f) * wyz * rv[c].x;
            ggy += (j ? 1.f : -1.f) * wxz * rv[c].x;
            ggz += (k ? 1.f : -1.f) * wxy * rv[c].x;
        }
        // chain rule through u = p / CELL
        ggx = ggx / CELL_;
        ggy = ggy / CELL_;
        ggz = ggz / CELL_;
    }

    // normals (invalid lanes: 0/EPS = 0, masked by wgt=0 anyway)
    const float gl = sqrtf(ggx * ggx + ggy * ggy + ggz * ggz);
    const float gd = fmaxf(gl, EPS_);
    const float nx = ggx / gd, ny = ggy / gd, nz = ggz / gd;

    // Laplace-CDF density
    const float sdf = emb0;
    const float sg  = (sdf > 0.f) ? 1.f : ((sdf < 0.f) ? -1.f : 0.f);
    float sigma = (0.5f + 0.5f * sg * expm1f(-fabsf(sdf) / b)) * (1.0f / b);
    sigma = valid ? sigma : 0.f;
    const float tau = sigma * DT_;

    // inclusive scan of tau: wave shfl_up scan + cross-wave offsets
    float incl = tau;
#pragma unroll
    for (int off = 1; off < 64; off <<= 1) {
        const float t = __shfl_up(incl, off, 64);
        if (lane >= off) incl += t;
    }
    if (lane == 63) s_wsum[wid] = incl;
    __syncthreads();
    float woff = 0.f;
    for (int i = 0; i < wid; ++i) woff += s_wsum[i];
    incl += woff;

    const float trans = expf(-(incl - tau));
    const float alpha = -expm1f(-tau);
    const float wgt   = valid ? trans * alpha : 0.f;

    // 8-channel weighted reduce: rgb(3), w*tm, nrm(3), acc
    float a0 = wgt * emb1;
    float a1 = wgt * emb2;
    float a2 = wgt * emb3;
    float a3 = wgt * tm;
    float a4 = wgt * nx;
    float a5 = wgt * ny;
    float a6 = wgt * nz;
    float a7 = wgt;

#pragma unroll
    for (int m = 1; m < 64; m <<= 1) {
        a0 += __shfl_xor(a0, m, 64);
        a1 += __shfl_xor(a1, m, 64);
        a2 += __shfl_xor(a2, m, 64);
        a3 += __shfl_xor(a3, m, 64);
        a4 += __shfl_xor(a4, m, 64);
        a5 += __shfl_xor(a5, m, 64);
        a6 += __shfl_xor(a6, m, 64);
        a7 += __shfl_xor(a7, m, 64);
    }
    if (lane == 0) {
        s_red[wid][0] = a0; s_red[wid][1] = a1;
        s_red[wid][2] = a2; s_red[wid][3] = a3;
        s_red[wid][4] = a4; s_red[wid][5] = a5;
        s_red[wid][6] = a6; s_red[wid][7] = a7;
    }
    __syncthreads();
    if (tid < 8) {
        float acc = s_red[0][tid] + s_red[1][tid] + s_red[2][tid] + s_red[3][tid];
        if (tid == 3) acc /= rays_d_norm[r];   // depth channel
        out[r * 8 + tid] = acc;
    }
}

extern "C" void kernel_launch(void* const* d_in, const int* in_sizes, int n_in,
                              void* d_out, int out_size, void* d_ws, size_t ws_size,
                              hipStream_t stream) {
    const float* rays_o      = (const float*)d_in[0];
    const float* rays_d      = (const float*)d_in[1];
    const float* rays_d_norm = (const float*)d_in[2];
    const float* nearv       = (const float*)d_in[3];
    const float* farv        = (const float*)d_in[4];
    const float* table       = (const float*)d_in[5];
    const float* betav       = (const float*)d_in[6];
    float* out = (float*)d_out;

    pv_render<<<dim3(R_), dim3(256), 0, stream>>>(
        rays_o, rays_d, rays_d_norm, nearv, farv, table, betav, out);
}